// Round 1
// baseline (1559.209 us; speedup 1.0000x reference)
//
#include <hip/hip_runtime.h>

typedef _Float16 v8h __attribute__((ext_vector_type(8)));
typedef _Float16 v4h __attribute__((ext_vector_type(4)));
typedef float v4f __attribute__((ext_vector_type(4)));

#define BM 128
#define BN 128
#define BK 32
#define LDK 40   // padded LDS row stride (fp16 elems): 80B rows, 16B-aligned

// ---------------------------------------------------------------------------
// Kernel 1: Y[m,n] = sum_k X[m,k] * W[n,k] + bias[n]   (fp32 in, fp16 MFMA)
// ---------------------------------------------------------------------------
__global__ __launch_bounds__(256) void gemm_bias_f16(
    const float* __restrict__ X,     // [M, K]
    const float* __restrict__ Wt,    // [N, K]
    const float* __restrict__ bias,  // [N]
    float* __restrict__ Y,           // [M, N]
    int M, int N, int K)
{
    __shared__ _Float16 As[BM * LDK];
    __shared__ _Float16 Bs[BN * LDK];

    const int tid  = threadIdx.x;
    const int lane = tid & 63;
    const int wave = tid >> 6;
    const int wy   = wave >> 1;   // M-half of wave
    const int wx   = wave & 1;    // N-half of wave
    const int lq   = lane >> 4;   // quad 0..3
    const int lr   = lane & 15;
    const int bm   = blockIdx.y * BM;
    const int bn   = blockIdx.x * BN;

    v4f acc[4][4];
    #pragma unroll
    for (int i = 0; i < 4; ++i)
        #pragma unroll
        for (int j = 0; j < 4; ++j)
            acc[i][j] = (v4f){0.f, 0.f, 0.f, 0.f};

    for (int k0 = 0; k0 < K; k0 += BK) {
        __syncthreads();   // protect LDS from previous iteration's readers
        #pragma unroll
        for (int j = 0; j < 4; ++j) {
            int flat = j * 1024 + tid * 4;   // 0..4095, float4-granular
            int row  = flat >> 5;            // /32
            int col  = flat & 31;
            float4 va = *(const float4*)(X  + (size_t)(bm + row) * K + k0 + col);
            float4 vb = *(const float4*)(Wt + (size_t)(bn + row) * K + k0 + col);
            v4h ha, hb;
            ha[0] = (_Float16)va.x; ha[1] = (_Float16)va.y;
            ha[2] = (_Float16)va.z; ha[3] = (_Float16)va.w;
            hb[0] = (_Float16)vb.x; hb[1] = (_Float16)vb.y;
            hb[2] = (_Float16)vb.z; hb[3] = (_Float16)vb.w;
            *(v4h*)(As + row * LDK + col) = ha;
            *(v4h*)(Bs + row * LDK + col) = hb;
        }
        __syncthreads();

        v8h af[4], bf[4];
        #pragma unroll
        for (int im = 0; im < 4; ++im)
            af[im] = *(const v8h*)(As + (wy * 64 + im * 16 + lr) * LDK + lq * 8);
        #pragma unroll
        for (int in = 0; in < 4; ++in)
            bf[in] = *(const v8h*)(Bs + (wx * 64 + in * 16 + lr) * LDK + lq * 8);

        #pragma unroll
        for (int im = 0; im < 4; ++im)
            #pragma unroll
            for (int in = 0; in < 4; ++in)
                acc[im][in] = __builtin_amdgcn_mfma_f32_16x16x32_f16(
                    af[im], bf[in], acc[im][in], 0, 0, 0);
    }

    // Epilogue: D[reg r] = C[row=(lane>>4)*4+r][col=lane&15]  (verified mapping)
    #pragma unroll
    for (int in = 0; in < 4; ++in) {
        int col = bn + wx * 64 + in * 16 + lr;
        float bc = bias[col];
        #pragma unroll
        for (int im = 0; im < 4; ++im) {
            int row0 = bm + wy * 64 + im * 16 + lq * 4;
            #pragma unroll
            for (int r = 0; r < 4; ++r)
                Y[(size_t)(row0 + r) * N + col] = acc[im][in][r] + bc;
        }
    }
}

// ---------------------------------------------------------------------------
// Kernel 2: per row (4096): z = FWHT(y*flips)/64; q = cent[searchsorted(bp,z)];
//           out = FWHT(q)/64 * flips.  In-place on Y.
// H_4096 = H16 (x) H16 (x) H16 : register-local H16 + LDS exchanges.
// LDS skew phys = i + (i>>4) keeps every phase <= 2-way bank conflict.
// ---------------------------------------------------------------------------
__device__ __forceinline__ void h16(float* v) {
    #pragma unroll
    for (int h = 1; h < 16; h <<= 1) {
        #pragma unroll
        for (int i = 0; i < 16; ++i) {
            if ((i & h) == 0) {
                float a = v[i], b = v[i + h];
                v[i] = a + b;
                v[i + h] = a - b;
            }
        }
    }
}

__global__ __launch_bounds__(256) void fwht_quant_fwht(
    float* __restrict__ Y,           // [rows, 4096] in/out
    const float* __restrict__ flips, // [4096]
    const float* __restrict__ bp)    // [15]
{
    __shared__ float ld[4352];       // 4096 + 256 skew
    const int t = threadIdx.x;
    float* yrow = Y + (size_t)blockIdx.x * 4096;

    float bq[15];
    #pragma unroll
    for (int j = 0; j < 15; ++j) bq[j] = bp[j];   // uniform -> s_load

    float v[16];
    // ownership c: i = t*16 + j (contiguous), apply flips on load
    #pragma unroll
    for (int j = 0; j < 4; ++j) {
        float4 xv = *(const float4*)(yrow  + t * 16 + j * 4);
        float4 fv = *(const float4*)(flips + t * 16 + j * 4);
        v[j*4+0] = xv.x * fv.x; v[j*4+1] = xv.y * fv.y;
        v[j*4+2] = xv.z * fv.z; v[j*4+3] = xv.w * fv.w;
    }
    h16(v);  // stages h=1..8 (axis c)
    #pragma unroll
    for (int j = 0; j < 16; ++j) ld[t * 17 + j] = v[j];
    __syncthreads();
    {   // ownership b: i = a*256 + b*16 + c, a=t>>4, c=t&15
        const int a = t >> 4, c = t & 15;
        #pragma unroll
        for (int b = 0; b < 16; ++b) v[b] = ld[a * 272 + b * 17 + c];
        h16(v);  // stages h=16..128 (axis b)
        #pragma unroll
        for (int b = 0; b < 16; ++b) ld[a * 272 + b * 17 + c] = v[b];
    }
    __syncthreads();
    {   // ownership a: b=t>>4, c=t&15
        const int b = t >> 4, c = t & 15;
        #pragma unroll
        for (int a = 0; a < 16; ++a) v[a] = ld[a * 272 + b * 17 + c];
        h16(v);  // stages h=256..2048 (axis a) -> FWHT #1 complete
        // quantize: idx = #{bp < z} (searchsorted left), q = -3 + 0.4*idx
        #pragma unroll
        for (int j = 0; j < 16; ++j) {
            float z = v[j] * 0.015625f;
            int idx = 0;
            #pragma unroll
            for (int n = 0; n < 15; ++n) idx += (bq[n] < z) ? 1 : 0;
            v[j] = -3.0f + 0.4f * (float)idx;
        }
        h16(v);  // FWHT #2 axis a
        #pragma unroll
        for (int a = 0; a < 16; ++a) ld[a * 272 + b * 17 + c] = v[a];
    }
    __syncthreads();
    {   // ownership b again
        const int a = t >> 4, c = t & 15;
        #pragma unroll
        for (int b = 0; b < 16; ++b) v[b] = ld[a * 272 + b * 17 + c];
        h16(v);  // FWHT #2 axis b
        #pragma unroll
        for (int b = 0; b < 16; ++b) ld[a * 272 + b * 17 + c] = v[b];
    }
    __syncthreads();
    // ownership c: finish, scale + flips, store
    #pragma unroll
    for (int j = 0; j < 16; ++j) v[j] = ld[t * 17 + j];
    h16(v);  // FWHT #2 axis c
    #pragma unroll
    for (int j = 0; j < 4; ++j) {
        float4 fv = *(const float4*)(flips + t * 16 + j * 4);
        float4 ov;
        ov.x = v[j*4+0] * 0.015625f * fv.x;
        ov.y = v[j*4+1] * 0.015625f * fv.y;
        ov.z = v[j*4+2] * 0.015625f * fv.z;
        ov.w = v[j*4+3] * 0.015625f * fv.w;
        *(float4*)(yrow + t * 16 + j * 4) = ov;
    }
}

// ---------------------------------------------------------------------------
extern "C" void kernel_launch(void* const* d_in, const int* in_sizes, int n_in,
                              void* d_out, int out_size, void* d_ws, size_t ws_size,
                              hipStream_t stream) {
    const float* x     = (const float*)d_in[0];
    const float* W     = (const float*)d_in[1];
    const float* b     = (const float*)d_in[2];
    const float* flips = (const float*)d_in[3];
    const float* bp    = (const float*)d_in[4];
    float* out = (float*)d_out;

    const int N = in_sizes[2];            // 4096
    const int K = in_sizes[1] / N;        // 4096
    const int M = in_sizes[0] / K;        // 16384

    dim3 ggrid(N / BN, M / BM);
    gemm_bias_f16<<<ggrid, 256, 0, stream>>>(x, W, b, out, M, N, K);
    fwht_quant_fwht<<<M, 256, 0, stream>>>(out, flips, bp);
}

// Round 2
// 1318.858 us; speedup vs baseline: 1.1822x; 1.1822x over previous
//
#include <hip/hip_runtime.h>
#include <stdint.h>

typedef _Float16 v8h __attribute__((ext_vector_type(8)));
typedef _Float16 v4h __attribute__((ext_vector_type(4)));
typedef float v4f __attribute__((ext_vector_type(4)));

#define GLL16(gp, lp) __builtin_amdgcn_global_load_lds( \
    (const __attribute__((address_space(1))) void*)(gp), \
    (__attribute__((address_space(3))) void*)(lp), 16, 0, 0)

// ---------------------------------------------------------------------------
// fp32 -> fp16 pack (8 elems/thread, coalesced)
// ---------------------------------------------------------------------------
__global__ __launch_bounds__(256) void cvt_f32_f16(
    const float* __restrict__ in, _Float16* __restrict__ out, size_t n)
{
    size_t i = ((size_t)blockIdx.x * 256 + threadIdx.x) * 8;
    if (i >= n) return;
    float4 a = *(const float4*)(in + i);
    float4 b = *(const float4*)(in + i + 4);
    v8h h;
    h[0] = (_Float16)a.x; h[1] = (_Float16)a.y;
    h[2] = (_Float16)a.z; h[3] = (_Float16)a.w;
    h[4] = (_Float16)b.x; h[5] = (_Float16)b.y;
    h[6] = (_Float16)b.z; h[7] = (_Float16)b.w;
    *(v8h*)(out + i) = h;
}

// ---------------------------------------------------------------------------
// Main GEMM: fp16 operands in global, global_load_lds width-16 staging,
// BK=64, XOR-swizzled LDS (slot cphys = clog ^ (row&7)) -> 2-way-max banks.
// Y[m,n] = sum_k Xh[m,k]*Wh[n,k] + bias[n]
// ---------------------------------------------------------------------------
__global__ __launch_bounds__(256) void gemm_f16_lds(
    const _Float16* __restrict__ Xh,  // [M,K] fp16
    const _Float16* __restrict__ Wh,  // [N,K] fp16
    const float* __restrict__ bias,
    float* __restrict__ Y,
    int M, int N, int K)
{
    __shared__ _Float16 As[8192];   // 128 rows x 8 slots x 8 fp16 (16 KB)
    __shared__ _Float16 Bs[8192];

    const int tid  = threadIdx.x;
    const int lane = tid & 63;
    const int w    = tid >> 6;
    const int lq   = lane >> 4;
    const int lr   = lane & 15;
    const int wy   = w >> 1;
    const int wx   = w & 1;
    const int l8   = lane >> 3;
    const int c8   = lane & 7;
    const int bm   = blockIdx.y * 128;
    const int bn   = blockIdx.x * 128;

    v4f acc[4][4];
    #pragma unroll
    for (int i = 0; i < 4; ++i)
        #pragma unroll
        for (int j = 0; j < 4; ++j)
            acc[i][j] = (v4f){0.f, 0.f, 0.f, 0.f};

    for (int k0 = 0; k0 < K; k0 += 64) {
        __syncthreads();   // previous iteration's readers done
        #pragma unroll
        for (int ii = 0; ii < 4; ++ii) {
            const int chunk = w * 4 + ii;          // 0..15, wave-uniform
            const int r     = chunk * 8 + l8;      // tile row 0..127
            const int clog  = c8 ^ (r & 7);        // XOR swizzle
            GLL16(Xh + (size_t)(bm + r) * K + k0 + clog * 8, As + chunk * 512);
            GLL16(Wh + (size_t)(bn + r) * K + k0 + clog * 8, Bs + chunk * 512);
        }
        __syncthreads();   // compiler emits vmcnt(0) drain here

        #pragma unroll
        for (int s = 0; s < 2; ++s) {
            v8h af[4], bf[4];
            #pragma unroll
            for (int im = 0; im < 4; ++im) {
                const int r  = wy * 64 + im * 16 + lr;
                const int cp = (s * 4 + lq) ^ (r & 7);
                af[im] = *(const v8h*)(As + r * 64 + cp * 8);
            }
            #pragma unroll
            for (int in = 0; in < 4; ++in) {
                const int r  = wx * 64 + in * 16 + lr;
                const int cp = (s * 4 + lq) ^ (r & 7);
                bf[in] = *(const v8h*)(Bs + r * 64 + cp * 8);
            }
            #pragma unroll
            for (int im = 0; im < 4; ++im)
                #pragma unroll
                for (int in = 0; in < 4; ++in)
                    acc[im][in] = __builtin_amdgcn_mfma_f32_16x16x32_f16(
                        af[im], bf[in], acc[im][in], 0, 0, 0);
        }
    }

    // D[reg r] = C[row=(lane>>4)*4+r][col=lane&15]
    #pragma unroll
    for (int in = 0; in < 4; ++in) {
        const int col = bn + wx * 64 + in * 16 + lr;
        const float bc = bias[col];
        #pragma unroll
        for (int im = 0; im < 4; ++im) {
            const int row0 = bm + wy * 64 + im * 16 + lq * 4;
            #pragma unroll
            for (int r = 0; r < 4; ++r)
                Y[(size_t)(row0 + r) * N + col] = acc[im][in][r] + bc;
        }
    }
}

// ---------------------------------------------------------------------------
// Fallback GEMM (fp32 in, converts in-loop) if ws too small for fp16 copies.
// ---------------------------------------------------------------------------
#define BK 32
#define LDK 40
__global__ __launch_bounds__(256) void gemm_bias_f16(
    const float* __restrict__ X, const float* __restrict__ Wt,
    const float* __restrict__ bias, float* __restrict__ Y,
    int M, int N, int K)
{
    __shared__ _Float16 As[128 * LDK];
    __shared__ _Float16 Bs[128 * LDK];
    const int tid = threadIdx.x;
    const int lane = tid & 63, wave = tid >> 6;
    const int wy = wave >> 1, wx = wave & 1;
    const int lq = lane >> 4, lr = lane & 15;
    const int bm = blockIdx.y * 128, bn = blockIdx.x * 128;

    v4f acc[4][4];
    #pragma unroll
    for (int i = 0; i < 4; ++i)
        #pragma unroll
        for (int j = 0; j < 4; ++j)
            acc[i][j] = (v4f){0.f, 0.f, 0.f, 0.f};

    for (int k0 = 0; k0 < K; k0 += BK) {
        __syncthreads();
        #pragma unroll
        for (int j = 0; j < 4; ++j) {
            int flat = j * 1024 + tid * 4;
            int row = flat >> 5, col = flat & 31;
            float4 va = *(const float4*)(X  + (size_t)(bm + row) * K + k0 + col);
            float4 vb = *(const float4*)(Wt + (size_t)(bn + row) * K + k0 + col);
            v4h ha, hb;
            ha[0] = (_Float16)va.x; ha[1] = (_Float16)va.y;
            ha[2] = (_Float16)va.z; ha[3] = (_Float16)va.w;
            hb[0] = (_Float16)vb.x; hb[1] = (_Float16)vb.y;
            hb[2] = (_Float16)vb.z; hb[3] = (_Float16)vb.w;
            *(v4h*)(As + row * LDK + col) = ha;
            *(v4h*)(Bs + row * LDK + col) = hb;
        }
        __syncthreads();
        v8h af[4], bf[4];
        #pragma unroll
        for (int im = 0; im < 4; ++im)
            af[im] = *(const v8h*)(As + (wy * 64 + im * 16 + lr) * LDK + lq * 8);
        #pragma unroll
        for (int in = 0; in < 4; ++in)
            bf[in] = *(const v8h*)(Bs + (wx * 64 + in * 16 + lr) * LDK + lq * 8);
        #pragma unroll
        for (int im = 0; im < 4; ++im)
            #pragma unroll
            for (int in = 0; in < 4; ++in)
                acc[im][in] = __builtin_amdgcn_mfma_f32_16x16x32_f16(
                    af[im], bf[in], acc[im][in], 0, 0, 0);
    }
    #pragma unroll
    for (int in = 0; in < 4; ++in) {
        int col = bn + wx * 64 + in * 16 + lr;
        float bc = bias[col];
        #pragma unroll
        for (int im = 0; im < 4; ++im) {
            int row0 = bm + wy * 64 + im * 16 + lq * 4;
            #pragma unroll
            for (int r = 0; r < 4; ++r)
                Y[(size_t)(row0 + r) * N + col] = acc[im][in][r] + bc;
        }
    }
}

// ---------------------------------------------------------------------------
// FWHT -> quant -> FWHT, coalesced float4 global I/O.
// Phase ownership: P1 = bits {0,1,10,11}, P2 = bits {2..5}, P3 = bits {6..9}.
// LDS skew A(i) = i + 4*((i>>5)+(i>>8)) -> every phase <= 2-way / balanced.
// ---------------------------------------------------------------------------
#define LADDR(i) ((i) + 4 * (((i) >> 5) + ((i) >> 8)))

__device__ __forceinline__ void h4(float& a, float& b, float& c, float& d) {
    float t0 = a + b, t1 = a - b, t2 = c + d, t3 = c - d;
    a = t0 + t2; b = t1 + t3; c = t0 - t2; d = t1 - t3;
}

__device__ __forceinline__ void h16(float* v) {
    #pragma unroll
    for (int h = 1; h < 16; h <<= 1) {
        #pragma unroll
        for (int i = 0; i < 16; ++i) {
            if ((i & h) == 0) {
                float a = v[i], b = v[i + h];
                v[i] = a + b;
                v[i + h] = a - b;
            }
        }
    }
}

__global__ __launch_bounds__(256) void fwht_quant_fwht(
    float* __restrict__ Y, const float* __restrict__ flips,
    const float* __restrict__ bp)
{
    __shared__ float ld[4672];
    const int t = threadIdx.x;
    float* yrow = Y + (size_t)blockIdx.x * 4096;

    float bq[15];
    #pragma unroll
    for (int j = 0; j < 15; ++j) bq[j] = bp[j];

    float v[4][4];   // [j = bits 10,11][e = bits 0,1]
    #pragma unroll
    for (int j = 0; j < 4; ++j) {
        const int i = j * 1024 + t * 4;
        float4 xv = *(const float4*)(yrow + i);
        float4 fv = *(const float4*)(flips + i);
        v[j][0] = xv.x * fv.x; v[j][1] = xv.y * fv.y;
        v[j][2] = xv.z * fv.z; v[j][3] = xv.w * fv.w;
    }
    #pragma unroll
    for (int j = 0; j < 4; ++j) h4(v[j][0], v[j][1], v[j][2], v[j][3]); // h=1,2
    #pragma unroll
    for (int e = 0; e < 4; ++e) h4(v[0][e], v[1][e], v[2][e], v[3][e]); // h=1024,2048
    #pragma unroll
    for (int j = 0; j < 4; ++j)
        *(float4*)(ld + LADDR(j * 1024 + t * 4)) = *(float4*)&v[j][0];
    __syncthreads();

    float u[16];
    {   // P2: bits 2..5 (h = 4,8,16,32)
        const int base = (t & 3) + 64 * (t >> 2);
        #pragma unroll
        for (int m = 0; m < 16; ++m) u[m] = ld[LADDR(base + 4 * m)];
        h16(u);
        #pragma unroll
        for (int m = 0; m < 16; ++m) ld[LADDR(base + 4 * m)] = u[m];
    }
    __syncthreads();
    {   // P3: bits 6..9 (h = 64..512); FWHT#1 complete here -> quant -> FWHT#2
        const int base = (t & 63) + 1024 * (t >> 6);
        #pragma unroll
        for (int m = 0; m < 16; ++m) u[m] = ld[LADDR(base + 64 * m)];
        h16(u);
        #pragma unroll
        for (int m = 0; m < 16; ++m) {
            float z = u[m] * 0.015625f;
            int idx = 0;
            #pragma unroll
            for (int n = 0; n < 15; ++n) idx += (bq[n] < z) ? 1 : 0;
            u[m] = -3.0f + 0.4f * (float)idx;
        }
        h16(u);
        #pragma unroll
        for (int m = 0; m < 16; ++m) ld[LADDR(base + 64 * m)] = u[m];
    }
    __syncthreads();
    {   // P2' (h = 4..32)
        const int base = (t & 3) + 64 * (t >> 2);
        #pragma unroll
        for (int m = 0; m < 16; ++m) u[m] = ld[LADDR(base + 4 * m)];
        h16(u);
        #pragma unroll
        for (int m = 0; m < 16; ++m) ld[LADDR(base + 4 * m)] = u[m];
    }
    __syncthreads();
    // P1' (h = 1,2,1024,2048) + scale + flips + coalesced store
    #pragma unroll
    for (int j = 0; j < 4; ++j)
        *(float4*)&v[j][0] = *(const float4*)(ld + LADDR(j * 1024 + t * 4));
    #pragma unroll
    for (int j = 0; j < 4; ++j) h4(v[j][0], v[j][1], v[j][2], v[j][3]);
    #pragma unroll
    for (int e = 0; e < 4; ++e) h4(v[0][e], v[1][e], v[2][e], v[3][e]);
    #pragma unroll
    for (int j = 0; j < 4; ++j) {
        const int i = j * 1024 + t * 4;
        float4 fv = *(const float4*)(flips + i);
        float4 ov;
        ov.x = v[j][0] * 0.015625f * fv.x;
        ov.y = v[j][1] * 0.015625f * fv.y;
        ov.z = v[j][2] * 0.015625f * fv.z;
        ov.w = v[j][3] * 0.015625f * fv.w;
        *(float4*)(yrow + i) = ov;
    }
}

// ---------------------------------------------------------------------------
extern "C" void kernel_launch(void* const* d_in, const int* in_sizes, int n_in,
                              void* d_out, int out_size, void* d_ws, size_t ws_size,
                              hipStream_t stream) {
    const float* x     = (const float*)d_in[0];
    const float* W     = (const float*)d_in[1];
    const float* b     = (const float*)d_in[2];
    const float* flips = (const float*)d_in[3];
    const float* bp    = (const float*)d_in[4];
    float* out = (float*)d_out;

    const int N = in_sizes[2];            // 4096
    const int K = in_sizes[1] / N;        // 4096
    const int M = in_sizes[0] / K;        // 16384

    const size_t nX = (size_t)M * K;
    const size_t nW = (size_t)N * K;
    const size_t need = (nX + nW) * sizeof(_Float16);

    dim3 ggrid(N / 128, M / 128);
    if (ws_size >= need) {
        _Float16* Xh = (_Float16*)d_ws;
        _Float16* Wh = Xh + nX;
        cvt_f32_f16<<<(int)(nX / 2048), 256, 0, stream>>>(x, Xh, nX);
        cvt_f32_f16<<<(int)(nW / 2048), 256, 0, stream>>>(W, Wh, nW);
        gemm_f16_lds<<<ggrid, 256, 0, stream>>>(Xh, Wh, b, out, M, N, K);
    } else {
        gemm_bias_f16<<<ggrid, 256, 0, stream>>>(x, W, b, out, M, N, K);
    }
    fwht_quant_fwht<<<M, 256, 0, stream>>>(out, flips, bp);
}